// Round 1
// baseline (60.075 us; speedup 1.0000x reference)
//
#include <hip/hip_runtime.h>
#include <math.h>
#include <float.h>

#define OFFSET_X 1.0f
#define OFFSET_Y 0.3f
#define T_HORIZON 5.0f

__global__ __launch_bounds__(256) void BackupBarrierCBF_kernel(
    const float* __restrict__ data, float* __restrict__ out, int n)
{
    int i = blockIdx.x * blockDim.x + threadIdx.x;
    if (i >= n) return;

    const float* p = data + (size_t)i * 15;
    float ex0  = p[0],  ey0 = p[1],  eyaw = p[2],  ev = p[3];
    float ax0  = p[4],  ay0 = p[5],  ayaw = p[6],  av = p[7];
    float eL   = p[8],  eW  = p[9];
    float aL   = p[11], aW  = p[12];
    float dt   = p[14];

    int n_t = (int)roundf(T_HORIZON / dt);

    float ce, se, ca, sa;
    sincosf(eyaw, &se, &ce);
    sincosf(ayaw, &sa, &ca);

    // Per-step relative velocity (agent - ego), rotated into ego frame, scaled by dt.
    float dvx = av * ca - ev * ce;
    float dvy = av * sa - ev * se;
    float dX  = ( dvx * ce + dvy * se) * dt;
    float dY  = (-dvx * se + dvy * ce) * dt;

    float rx0 = ax0 - ex0;
    float ry0 = ay0 - ey0;

    float hx = 0.5f * eL + OFFSET_X;
    float hy = 0.5f * eW + OFFSET_Y;
    float hcx = 0.5f * aL;
    float hcy = 0.5f * aW;

    // Agent box corners in ego frame at t=0 (sx = {+,+,-,-}, sy = {+,-,+,-}).
    float X[4], Y[4];
#pragma unroll
    for (int k = 0; k < 4; ++k) {
        float cx = (k < 2)        ?  hcx : -hcx;
        float cy = ((k & 1) == 0) ?  hcy : -hcy;
        float wx = rx0 + cx * ca - cy * sa;
        float wy = ry0 + cx * sa + cy * ca;
        X[k] =  wx * ce + wy * se;
        Y[k] = -wx * se + wy * ce;
    }

    float m = FLT_MAX;
    for (int t = 0; t < n_t; ++t) {
#pragma unroll
        for (int k = 0; k < 4; ++k) {
            X[k] += dX;
            Y[k] += dY;
            float d = fmaxf(fabsf(X[k]) - hx, fabsf(Y[k]) - hy);
            m = fminf(m, d);
        }
    }

    // (sigmoid(m/5) - 0.5) * 10
    float s = 1.0f / (1.0f + expf(-m * 0.2f));
    out[i] = (s - 0.5f) * 10.0f;
}

extern "C" void kernel_launch(void* const* d_in, const int* in_sizes, int n_in,
                              void* d_out, int out_size, void* d_ws, size_t ws_size,
                              hipStream_t stream) {
    const float* data = (const float*)d_in[0];
    float* out = (float*)d_out;
    int n = out_size;  // B*A = 4096*32 = 131072
    int block = 256;
    int grid = (n + block - 1) / block;
    BackupBarrierCBF_kernel<<<grid, block, 0, stream>>>(data, out, n);
}